// Round 8
// baseline (775.571 us; speedup 1.0000x reference)
//
#include <hip/hip_runtime.h>
#include <hip/hip_bf16.h>

#define VOUT 50257
#define KHOT 1024
#define DIM  1024
#define RHOT 384
#define RCOLD 32
#define RF   416   // RHOT + RCOLD

typedef __attribute__((ext_vector_type(8))) short short8;
typedef __attribute__((ext_vector_type(4))) float f32x4;

// ---------------- K0: convert f32 weights to bf16 ----------------
__global__ void k_convert(const float* __restrict__ Bh, const float* __restrict__ Bc,
                          const float* __restrict__ Uh, const float* __restrict__ Uc,
                          __hip_bfloat16* __restrict__ Bmat,
                          __hip_bfloat16* __restrict__ UhB,
                          __hip_bfloat16* __restrict__ UcB) {
  const int nBh = RHOT * DIM;            // 393216
  const int nBm = RF * DIM;              // 425984
  const int nUh = KHOT * RHOT;           // 393216
  const int nUc = (VOUT - KHOT) * RCOLD; // 1575456
  const int total = nBm + nUh + nUc;
  for (int i = blockIdx.x * blockDim.x + threadIdx.x; i < total;
       i += gridDim.x * blockDim.x) {
    if (i < nBm) {
      float v = (i < nBh) ? Bh[i] : Bc[i - nBh];
      Bmat[i] = __float2bfloat16(v);
    } else if (i < nBm + nUh) {
      UhB[i - nBm] = __float2bfloat16(Uh[i - nBm]);
    } else {
      int j = i - nBm - nUh;
      UcB[j] = __float2bfloat16(Uc[j]);
    }
  }
}

// ---------------- K1: G = Bmat @ Bmat^T  (416x416, K=1024), f32 out ----------------
__global__ __launch_bounds__(256) void k_gram(const __hip_bfloat16* __restrict__ Bmat,
                                              float* __restrict__ G) {
  const int wave = threadIdx.x >> 6;
  const int lane = threadIdx.x & 63;
  const int idx = blockIdx.x * 4 + wave;
  if (idx >= 26 * 26) return;  // wave-uniform
  const int ti = idx / 26, tj = idx % 26;
  const int i0 = ti * 16, j0 = tj * 16;
  const int col16 = lane & 15;
  const int g4 = lane >> 4;

  f32x4 acc = (f32x4){0.f, 0.f, 0.f, 0.f};
  const __hip_bfloat16* arow = Bmat + (size_t)(i0 + col16) * DIM;
  const __hip_bfloat16* brow = Bmat + (size_t)(j0 + col16) * DIM;
#pragma unroll 4
  for (int ks = 0; ks < DIM / 32; ++ks) {
    short8 a = *reinterpret_cast<const short8*>(arow + ks * 32 + g4 * 8);
    short8 b = *reinterpret_cast<const short8*>(brow + ks * 32 + g4 * 8);
    acc = __builtin_amdgcn_mfma_f32_16x16x32_bf16(a, b, acc, 0, 0, 0);
  }
#pragma unroll
  for (int r = 0; r < 4; ++r)
    G[(size_t)(i0 + g4 * 4 + r) * RF + j0 + col16] = acc[r];
}

// ---------------- K2: per-token F[n] = u @ G  (f32 math, bf16 out) ----------------
__global__ void k_encode(const int* __restrict__ tokens, const int* __restrict__ o2n,
                         const float* __restrict__ Uh, const float* __restrict__ Uc,
                         const float* __restrict__ G, __hip_bfloat16* __restrict__ F) {
  const int n = blockIdx.x;
  __shared__ float u[RHOT];
  const int tok = tokens[n];
  const int tn = o2n[tok];
  const bool hot = tn < KHOT;
  const int R = hot ? RHOT : RCOLD;
  const float* urow = hot ? (Uh + (size_t)tn * RHOT) : (Uc + (size_t)(tn - KHOT) * RCOLD);
  for (int r = threadIdx.x; r < R; r += blockDim.x) u[r] = urow[r];
  __syncthreads();
  const int gbase = hot ? 0 : RHOT;
  for (int c = threadIdx.x; c < RF; c += blockDim.x) {
    float acc = 0.f;
    for (int r = 0; r < R; ++r) acc += u[r] * G[(size_t)(gbase + r) * RF + c];
    F[(size_t)n * RF + c] = __float2bfloat16(acc);
  }
}

// ---------------- K3 v8: swapped-operand MFMA -> direct row-major stores ----------------
// D = mfma(A=W_frag, B=F_frag): D's col16 = token, reg-dim = vocab -> each lane's
// 4 accs are 4 CONSECUTIVE output columns of one row -> direct dwordx4 store.
// No LDS, no barriers, no transpose. Wave owns 16 rows x 1024-col window; sweeps
// 64 subtiles in ascending v -> each row receives sequential 64B chunks issued
// back-to-back (L2 write-combines into full lines). F b-frag is loop-invariant
// (4 VGPRs). Grid (50, 64), 4 waves/block, ~full occupancy.
#define CW 1024

__global__ __launch_bounds__(256) void k_out(const int* __restrict__ o2n,
                                             const __hip_bfloat16* __restrict__ F,
                                             const __hip_bfloat16* __restrict__ Uh,
                                             const __hip_bfloat16* __restrict__ Uc,
                                             const float* __restrict__ log_alpha,
                                             const float* __restrict__ bias,
                                             float* __restrict__ out) {
  const int tid = threadIdx.x;
  const int wave = tid >> 6;
  const int lane = tid & 63;
  const int col16 = lane & 15;   // token index within wave (A.. B-frag row; D col)
  const int g4 = lane >> 4;      // k-chunk for frags; vocab-quad for D
  const int n = blockIdx.y * 64 + wave * 16 + col16;  // this lane's token row
  const int v0w = blockIdx.x * CW;
  const float alpha = expf(log_alpha[0]);
  const short8 zero8 = (short8){0, 0, 0, 0, 0, 0, 0, 0};

  const __hip_bfloat16* Frow = F + (size_t)n * RF;
  const short8 fcold = *reinterpret_cast<const short8*>(Frow + RHOT + g4 * 8);  // loop-invariant
  const size_t outrow = (size_t)n * VOUT;

  const int rem = (VOUT - v0w + 15) >> 4;
  const int nsub = (CW >> 4) < rem ? (CW >> 4) : rem;

  for (int s = 0; s < nsub; ++s) {
    const int v0 = v0w + s * 16;
    const int vl = v0 + col16;
    const int src = o2n[(vl < VOUT) ? vl : (VOUT - 1)];

    f32x4 acc = (f32x4){0.f, 0.f, 0.f, 0.f};

    // cold: K = 32  (A = Uc rows, B = F cold slice)
    if (__any(src >= KHOT)) {
      short8 aw = zero8;
      if (src >= KHOT)
        aw = *reinterpret_cast<const short8*>(Uc + (size_t)(src - KHOT) * RCOLD + g4 * 8);
      acc = __builtin_amdgcn_mfma_f32_16x16x32_bf16(aw, fcold, acc, 0, 0, 0);
    }
    // hot: K = 384 (rare: ~2% of subtiles with identity perm)
    if (__any(src < KHOT)) {
#pragma unroll
      for (int ks = 0; ks < RHOT / 32; ++ks) {
        short8 aw = zero8;
        if (src < KHOT)
          aw = *reinterpret_cast<const short8*>(Uh + (size_t)src * RHOT + ks * 32 + g4 * 8);
        const short8 fh = *reinterpret_cast<const short8*>(Frow + ks * 32 + g4 * 8);
        acc = __builtin_amdgcn_mfma_f32_16x16x32_bf16(aw, fh, acc, 0, 0, 0);
      }
    }

    // store: lane's 4 accs = 4 consecutive vocab columns of row n
    const int vs = v0 + g4 * 4;
    if (vs + 3 < VOUT) {
      const f32x4 b4 = *reinterpret_cast<const f32x4*>(bias + vs);
      f32x4 vals = acc * alpha + b4;
      *reinterpret_cast<f32x4*>(out + outrow + vs) = vals;
    } else {
#pragma unroll
      for (int r = 0; r < 4; ++r)
        if (vs + r < VOUT) out[outrow + vs + r] = acc[r] * alpha + bias[vs + r];
    }
  }
}

extern "C" void kernel_launch(void* const* d_in, const int* in_sizes, int n_in,
                              void* d_out, int out_size, void* d_ws, size_t ws_size,
                              hipStream_t stream) {
  const int* tokens    = (const int*)d_in[0];
  const int* o2n       = (const int*)d_in[1];
  const float* B_hot   = (const float*)d_in[2];
  const float* B_cold  = (const float*)d_in[3];
  const float* U_hot   = (const float*)d_in[4];
  const float* U_cold  = (const float*)d_in[5];
  const float* log_a   = (const float*)d_in[6];
  const float* bias    = (const float*)d_in[7];
  float* out = (float*)d_out;

  const int N = in_sizes[0];  // 4096 tokens

  // workspace layout (bytes)
  char* ws = (char*)d_ws;
  __hip_bfloat16* Bmat = (__hip_bfloat16*)(ws + 0);             // 425984*2
  __hip_bfloat16* UhB  = (__hip_bfloat16*)(ws + (1u << 20));    // 393216*2
  __hip_bfloat16* UcB  = (__hip_bfloat16*)(ws + (2u << 20));    // 1575456*2
  float*          G    = (float*)(ws + (6u << 20));             // 416*416*4
  __hip_bfloat16* F    = (__hip_bfloat16*)(ws + (7u << 20));    // 4096*416*2

  k_convert<<<2048, 256, 0, stream>>>(B_hot, B_cold, U_hot, U_cold, Bmat, UhB, UcB);
  k_gram<<<169, 256, 0, stream>>>(Bmat, G);
  k_encode<<<N, 256, 0, stream>>>(tokens, o2n, U_hot, U_cold, G, F);

  dim3 grid((VOUT + CW - 1) / CW, N / 64);
  k_out<<<grid, 256, 0, stream>>>(o2n, F, UhB, UcB, log_a, bias, out);
}

// Round 9
// 599.770 us; speedup vs baseline: 1.2931x; 1.2931x over previous
//
#include <hip/hip_runtime.h>
#include <hip/hip_bf16.h>

#define VOUT 50257
#define KHOT 1024
#define DIM  1024
#define RHOT 384
#define RCOLD 32
#define RF   416   // RHOT + RCOLD

typedef __attribute__((ext_vector_type(8))) short short8;
typedef __attribute__((ext_vector_type(4))) float f32x4;

__device__ __forceinline__ int delta_row(int n) {
  // smallest d>=0 with 17*n + d ≡ 0 (mod 32)  => byte addr of col (c0+d) is 128B-aligned
  return (32 - ((17 * n) & 31)) & 31;
}

// ---------------- K0: convert f32 weights to bf16 ----------------
__global__ void k_convert(const float* __restrict__ Bh, const float* __restrict__ Bc,
                          const float* __restrict__ Uh, const float* __restrict__ Uc,
                          __hip_bfloat16* __restrict__ Bmat,
                          __hip_bfloat16* __restrict__ UhB,
                          __hip_bfloat16* __restrict__ UcB) {
  const int nBh = RHOT * DIM;            // 393216
  const int nBm = RF * DIM;              // 425984
  const int nUh = KHOT * RHOT;           // 393216
  const int nUc = (VOUT - KHOT) * RCOLD; // 1575456
  const int total = nBm + nUh + nUc;
  for (int i = blockIdx.x * blockDim.x + threadIdx.x; i < total;
       i += gridDim.x * blockDim.x) {
    if (i < nBm) {
      float v = (i < nBh) ? Bh[i] : Bc[i - nBh];
      Bmat[i] = __float2bfloat16(v);
    } else if (i < nBm + nUh) {
      UhB[i - nBm] = __float2bfloat16(Uh[i - nBm]);
    } else {
      int j = i - nBm - nUh;
      UcB[j] = __float2bfloat16(Uc[j]);
    }
  }
}

// ---------------- K1: G = Bmat @ Bmat^T  (416x416, K=1024), f32 out ----------------
__global__ __launch_bounds__(256) void k_gram(const __hip_bfloat16* __restrict__ Bmat,
                                              float* __restrict__ G) {
  const int wave = threadIdx.x >> 6;
  const int lane = threadIdx.x & 63;
  const int idx = blockIdx.x * 4 + wave;
  if (idx >= 26 * 26) return;  // wave-uniform
  const int ti = idx / 26, tj = idx % 26;
  const int i0 = ti * 16, j0 = tj * 16;
  const int col16 = lane & 15;
  const int g4 = lane >> 4;

  f32x4 acc = (f32x4){0.f, 0.f, 0.f, 0.f};
  const __hip_bfloat16* arow = Bmat + (size_t)(i0 + col16) * DIM;
  const __hip_bfloat16* brow = Bmat + (size_t)(j0 + col16) * DIM;
#pragma unroll 4
  for (int ks = 0; ks < DIM / 32; ++ks) {
    short8 a = *reinterpret_cast<const short8*>(arow + ks * 32 + g4 * 8);
    short8 b = *reinterpret_cast<const short8*>(brow + ks * 32 + g4 * 8);
    acc = __builtin_amdgcn_mfma_f32_16x16x32_bf16(a, b, acc, 0, 0, 0);
  }
#pragma unroll
  for (int r = 0; r < 4; ++r)
    G[(size_t)(i0 + g4 * 4 + r) * RF + j0 + col16] = acc[r];
}

// ---------------- K2: per-token F[n] = u @ G  (f32 math, bf16 out) ----------------
__global__ void k_encode(const int* __restrict__ tokens, const int* __restrict__ o2n,
                         const float* __restrict__ Uh, const float* __restrict__ Uc,
                         const float* __restrict__ G, __hip_bfloat16* __restrict__ F) {
  const int n = blockIdx.x;
  __shared__ float u[RHOT];
  const int tok = tokens[n];
  const int tn = o2n[tok];
  const bool hot = tn < KHOT;
  const int R = hot ? RHOT : RCOLD;
  const float* urow = hot ? (Uh + (size_t)tn * RHOT) : (Uc + (size_t)(tn - KHOT) * RCOLD);
  for (int r = threadIdx.x; r < R; r += blockDim.x) u[r] = urow[r];
  __syncthreads();
  const int gbase = hot ? 0 : RHOT;
  for (int c = threadIdx.x; c < RF; c += blockDim.x) {
    float acc = 0.f;
    for (int r = 0; r < R; ++r) acc += u[r] * G[(size_t)(gbase + r) * RF + c];
    F[(size_t)n * RF + c] = __float2bfloat16(acc);
  }
}

// ---------------- K3 v9: per-row 128B-ALIGNED store windows ----------------
// Block = 64 rows x 1024 stored cols. Row n's window is [c0+d(n), c0+1024+d(n)),
// d(n) = (-17n) mod 32, so EVERY 1KB store instruction is 128B-aligned (8 full
// lines, zero partials). c0 ≡ 0 mod 32 -> d is block-independent -> blocks tile
// each row seamlessly. Compute covers [c0, c0+1056); Epi holds the shifted
// window (scatter write p = col - d(row)); store reads are aligned ds_read_b128.
// Raw s_barrier + lgkmcnt only (NO vmcnt drain in loop) -> stores stay in flight.
// Row head [0, d(n)) handled by scalar cleanup in bx==0 blocks.
#define CPB 1024
#define RPB 64
#define NSUB 66      // computed subtiles = 1056 cols
#define EPIT 1028    // Epi pitch (f32); row stride 4112B ≡ 0 mod 16

__global__ __launch_bounds__(256) void k_out(const int* __restrict__ o2n,
                                             const __hip_bfloat16* __restrict__ F,
                                             const __hip_bfloat16* __restrict__ Uh,
                                             const __hip_bfloat16* __restrict__ Uc,
                                             const float* __restrict__ log_alpha,
                                             const float* __restrict__ bias,
                                             float* __restrict__ out) {
  __shared__ __hip_bfloat16 Fc[RPB][40];  // cold F slice, 5.1 KB
  __shared__ float Epi[16][EPIT];         // 65.8 KB
  const int tid = threadIdx.x;
  const int wave = tid >> 6;
  const int lane = tid & 63;
  const int col16 = lane & 15;
  const int g4 = lane >> 4;
  const int n0 = blockIdx.y * RPB;
  const int c0 = blockIdx.x * CPB;
  const float alpha = expf(log_alpha[0]);
  const short8 zero8 = (short8){0, 0, 0, 0, 0, 0, 0, 0};

  // stage cold F slice (64 rows x 32 cols)
  {
    const int row = tid >> 2, ch = tid & 3;
    *reinterpret_cast<short8*>(&Fc[row][ch * 8]) =
        *reinterpret_cast<const short8*>(F + (size_t)(n0 + row) * RF + RHOT + ch * 8);
  }

  // per-wave subtile metadata: st = 4*i + wave, i = 0..16 (st < 66)
  int srcs[17];
  float bv[17];
  unsigned hotm = 0, coldm = 0;
#pragma unroll
  for (int i = 0; i < 17; ++i) {
    const int st = 4 * i + wave;
    if (st >= NSUB) { srcs[i] = 0; bv[i] = 0.f; continue; }
    const int v = c0 + st * 16 + col16;
    const int vc = (v < VOUT) ? v : (VOUT - 1);
    srcs[i] = o2n[vc];
    bv[i] = bias[vc];
    if (__any(srcs[i] < KHOT)) hotm |= (1u << i);
    if (__any(srcs[i] >= KHOT)) coldm |= (1u << i);
  }
  __syncthreads();  // Fc ready

  for (int t = 0; t < 4; ++t) {
    // per-lane write shifts for the 4 accumulator rows
    int dw[4];
#pragma unroll
    for (int r = 0; r < 4; ++r) dw[r] = delta_row(n0 + t * 16 + g4 * 4 + r);

    // ---- compute + Epi scatter-write ----
    for (int i = 0; i < 17; ++i) {
      const int st = 4 * i + wave;
      if (st >= NSUB) break;
      f32x4 acc = (f32x4){0.f, 0.f, 0.f, 0.f};
      if (coldm & (1u << i)) {
        const short8 afc = *reinterpret_cast<const short8*>(&Fc[t * 16 + col16][g4 * 8]);
        short8 bfrag = zero8;
        if (srcs[i] >= KHOT)
          bfrag = *reinterpret_cast<const short8*>(Uc + (size_t)(srcs[i] - KHOT) * RCOLD + g4 * 8);
        acc = __builtin_amdgcn_mfma_f32_16x16x32_bf16(afc, bfrag, acc, 0, 0, 0);
      }
      if (hotm & (1u << i)) {
#pragma unroll
        for (int ks = 0; ks < RHOT / 32; ++ks) {
          const short8 afh = *reinterpret_cast<const short8*>(
              F + (size_t)(n0 + t * 16 + col16) * RF + ks * 32 + g4 * 8);
          short8 bfrag = zero8;
          if (srcs[i] < KHOT)
            bfrag = *reinterpret_cast<const short8*>(Uh + (size_t)srcs[i] * RHOT + ks * 32 + g4 * 8);
          acc = __builtin_amdgcn_mfma_f32_16x16x32_bf16(afh, bfrag, acc, 0, 0, 0);
        }
      }
#pragma unroll
      for (int r = 0; r < 4; ++r) {
        const int p = st * 16 + col16 - dw[r];
        if (p >= 0 && p < CPB)
          Epi[g4 * 4 + r][p] = acc[r] * alpha + bv[i];
      }
    }

    // barrier: Epi writes visible; do NOT drain stores (vmcnt untouched)
    asm volatile("s_waitcnt lgkmcnt(0)" ::: "memory");
    __builtin_amdgcn_sched_barrier(0);
    __builtin_amdgcn_s_barrier();
    __builtin_amdgcn_sched_barrier(0);

    // ---- store phase: wave stores rows [4*wave, 4*wave+4), 4x 1KB aligned runs each ----
#pragma unroll
    for (int rr = 0; rr < 4; ++rr) {
      const int row16 = wave * 4 + rr;
      const int n = n0 + t * 16 + row16;
      const int dn = delta_row(n);
      const size_t gr = (size_t)n * VOUT;
      const int cb = c0 + dn;
#pragma unroll
      for (int j = 0; j < 4; ++j) {
        f32x4 vals = *reinterpret_cast<const f32x4*>(&Epi[row16][j * 256 + lane * 4]);
        const int c = cb + j * 256 + lane * 4;
        if (c + 3 < VOUT) {
          *reinterpret_cast<f32x4*>(out + gr + c) = vals;
        } else {
#pragma unroll
          for (int q = 0; q < 4; ++q)
            if (c + q < VOUT) out[gr + c + q] = vals[q];
        }
      }
    }

    // barrier: my LDS reads done; next chunk may overwrite Epi. Stores stay in flight.
    asm volatile("s_waitcnt lgkmcnt(0)" ::: "memory");
    __builtin_amdgcn_sched_barrier(0);
    __builtin_amdgcn_s_barrier();
    __builtin_amdgcn_sched_barrier(0);
  }

  // ---- head cleanup: cols [0, d(n)) for this block's rows (bx == 0 only) ----
  if (blockIdx.x == 0) {
    for (int idx = tid; idx < RPB * 32; idx += 256) {
      const int row = idx >> 5, cc = idx & 31;
      const int n = n0 + row;
      if (cc >= delta_row(n)) continue;
      const int src = o2n[cc];
      float sum = 0.f;
      if (src < KHOT) {
        const __hip_bfloat16* uh = Uh + (size_t)src * RHOT;
        const __hip_bfloat16* fr = F + (size_t)n * RF;
        for (int k = 0; k < RHOT; ++k)
          sum += __bfloat162float(uh[k]) * __bfloat162float(fr[k]);
      } else {
        const __hip_bfloat16* uc = Uc + (size_t)(src - KHOT) * RCOLD;
        const __hip_bfloat16* fr = F + (size_t)n * RF + RHOT;
        for (int k = 0; k < RCOLD; ++k)
          sum += __bfloat162float(uc[k]) * __bfloat162float(fr[k]);
      }
      out[(size_t)n * VOUT + cc] = sum * alpha + bias[cc];
    }
  }
}

extern "C" void kernel_launch(void* const* d_in, const int* in_sizes, int n_in,
                              void* d_out, int out_size, void* d_ws, size_t ws_size,
                              hipStream_t stream) {
  const int* tokens    = (const int*)d_in[0];
  const int* o2n       = (const int*)d_in[1];
  const float* B_hot   = (const float*)d_in[2];
  const float* B_cold  = (const float*)d_in[3];
  const float* U_hot   = (const float*)d_in[4];
  const float* U_cold  = (const float*)d_in[5];
  const float* log_a   = (const float*)d_in[6];
  const float* bias    = (const float*)d_in[7];
  float* out = (float*)d_out;

  const int N = in_sizes[0];  // 4096 tokens

  // workspace layout (bytes)
  char* ws = (char*)d_ws;
  __hip_bfloat16* Bmat = (__hip_bfloat16*)(ws + 0);             // 425984*2
  __hip_bfloat16* UhB  = (__hip_bfloat16*)(ws + (1u << 20));    // 393216*2
  __hip_bfloat16* UcB  = (__hip_bfloat16*)(ws + (2u << 20));    // 1575456*2
  float*          G    = (float*)(ws + (6u << 20));             // 416*416*4
  __hip_bfloat16* F    = (__hip_bfloat16*)(ws + (7u << 20));    // 4096*416*2

  k_convert<<<2048, 256, 0, stream>>>(B_hot, B_cold, U_hot, U_cold, Bmat, UhB, UcB);
  k_gram<<<169, 256, 0, stream>>>(Bmat, G);
  k_encode<<<N, 256, 0, stream>>>(tokens, o2n, U_hot, U_cold, G, F);

  dim3 grid((VOUT + CPB - 1) / CPB, N / RPB);
  k_out<<<grid, 256, 0, stream>>>(o2n, F, UhB, UcB, log_a, bias, out);
}

// Round 11
// 373.949 us; speedup vs baseline: 2.0740x; 1.6039x over previous
//
#include <hip/hip_runtime.h>
#include <hip/hip_bf16.h>

#define VOUT 50257
#define KHOT 1024
#define DIM  1024
#define RHOT 384
#define RCOLD 32
#define RF   416   // RHOT + RCOLD

typedef __attribute__((ext_vector_type(8))) short short8;
typedef __attribute__((ext_vector_type(4))) float f32x4;

__device__ __forceinline__ int delta_row(int n) {
  // smallest d>=0 with 17*n + d ≡ 0 (mod 32) => col (c0+d) of row n is 128B-aligned
  return (32 - ((17 * n) & 31)) & 31;
}

// ---------------- K0: convert f32 weights to bf16 ----------------
__global__ void k_convert(const float* __restrict__ Bh, const float* __restrict__ Bc,
                          const float* __restrict__ Uh, const float* __restrict__ Uc,
                          __hip_bfloat16* __restrict__ Bmat,
                          __hip_bfloat16* __restrict__ UhB,
                          __hip_bfloat16* __restrict__ UcB) {
  const int nBh = RHOT * DIM;            // 393216
  const int nBm = RF * DIM;              // 425984
  const int nUh = KHOT * RHOT;           // 393216
  const int nUc = (VOUT - KHOT) * RCOLD; // 1575456
  const int total = nBm + nUh + nUc;
  for (int i = blockIdx.x * blockDim.x + threadIdx.x; i < total;
       i += gridDim.x * blockDim.x) {
    if (i < nBm) {
      float v = (i < nBh) ? Bh[i] : Bc[i - nBh];
      Bmat[i] = __float2bfloat16(v);
    } else if (i < nBm + nUh) {
      UhB[i - nBm] = __float2bfloat16(Uh[i - nBm]);
    } else {
      int j = i - nBm - nUh;
      UcB[j] = __float2bfloat16(Uc[j]);
    }
  }
}

// ---------------- K1: G = Bmat @ Bmat^T  (416x416, K=1024), f32 out ----------------
__global__ __launch_bounds__(256) void k_gram(const __hip_bfloat16* __restrict__ Bmat,
                                              float* __restrict__ G) {
  const int wave = threadIdx.x >> 6;
  const int lane = threadIdx.x & 63;
  const int idx = blockIdx.x * 4 + wave;
  if (idx >= 26 * 26) return;  // wave-uniform
  const int ti = idx / 26, tj = idx % 26;
  const int i0 = ti * 16, j0 = tj * 16;
  const int col16 = lane & 15;
  const int g4 = lane >> 4;

  f32x4 acc = (f32x4){0.f, 0.f, 0.f, 0.f};
  const __hip_bfloat16* arow = Bmat + (size_t)(i0 + col16) * DIM;
  const __hip_bfloat16* brow = Bmat + (size_t)(j0 + col16) * DIM;
#pragma unroll 4
  for (int ks = 0; ks < DIM / 32; ++ks) {
    short8 a = *reinterpret_cast<const short8*>(arow + ks * 32 + g4 * 8);
    short8 b = *reinterpret_cast<const short8*>(brow + ks * 32 + g4 * 8);
    acc = __builtin_amdgcn_mfma_f32_16x16x32_bf16(a, b, acc, 0, 0, 0);
  }
#pragma unroll
  for (int r = 0; r < 4; ++r)
    G[(size_t)(i0 + g4 * 4 + r) * RF + j0 + col16] = acc[r];
}

// ---------------- K2: per-token F[n] = u @ G  (f32 math, bf16 out) ----------------
__global__ void k_encode(const int* __restrict__ tokens, const int* __restrict__ o2n,
                         const float* __restrict__ Uh, const float* __restrict__ Uc,
                         const float* __restrict__ G, __hip_bfloat16* __restrict__ F) {
  const int n = blockIdx.x;
  __shared__ float u[RHOT];
  const int tok = tokens[n];
  const int tn = o2n[tok];
  const bool hot = tn < KHOT;
  const int R = hot ? RHOT : RCOLD;
  const float* urow = hot ? (Uh + (size_t)tn * RHOT) : (Uc + (size_t)(tn - KHOT) * RCOLD);
  for (int r = threadIdx.x; r < R; r += blockDim.x) u[r] = urow[r];
  __syncthreads();
  const int gbase = hot ? 0 : RHOT;
  for (int c = threadIdx.x; c < RF; c += blockDim.x) {
    float acc = 0.f;
    for (int r = 0; r < R; ++r) acc += u[r] * G[(size_t)(gbase + r) * RF + c];
    F[(size_t)n * RF + c] = __float2bfloat16(acc);
  }
}

// ---------------- K3 v10: v3 issue engine + aligned windows + zero loads in loop ----------------
// Block = 64 rows x 256 STORED cols (computes 288 = 18 subtiles). Row n's window
// is [c0+d(n), c0+256+d(n)), d(n)=(-17n)%32 -> every 1KB store is 128B-aligned
// (8 full lines, no partials). d block-independent -> blocks tile rows seamlessly.
// ALL global data (o2n, bias, Uc b-frags) prefetched to registers at block top;
// the cold t-loop is pure {LDS, MFMA, store} -> stores never drained mid-block.
// Raw s_barrier + lgkmcnt(0) only (no vmcnt drain). 21.8KB LDS -> 7 blocks/CU.
#define CPB 256
#define RPB 64
#define NSUB 18
#define EPIT 260

__global__ __launch_bounds__(256) void k_out(const int* __restrict__ o2n,
                                             const __hip_bfloat16* __restrict__ F,
                                             const __hip_bfloat16* __restrict__ Uh,
                                             const __hip_bfloat16* __restrict__ Uc,
                                             const float* __restrict__ log_alpha,
                                             const float* __restrict__ bias,
                                             float* __restrict__ out) {
  __shared__ __hip_bfloat16 Fc[RPB][40];  // cold F slice (5.1 KB)
  __shared__ float Epi[16][EPIT];         // 16.6 KB
  const int tid = threadIdx.x;
  const int wave = tid >> 6;
  const int lane = tid & 63;
  const int col16 = lane & 15;
  const int g4 = lane >> 4;
  const int n0 = blockIdx.y * RPB;
  const int c0 = blockIdx.x * CPB;
  const float alpha = expf(log_alpha[0]);
  const short8 zero8 = (short8){0, 0, 0, 0, 0, 0, 0, 0};

  // stage cold F slice (64 rows x 32 cols; 16B/thread)
  {
    const int row = tid >> 2, ch = tid & 3;
    *reinterpret_cast<short8*>(&Fc[row][ch * 8]) =
        *reinterpret_cast<const short8*>(F + (size_t)(n0 + row) * RF + RHOT + ch * 8);
  }

  // prefetch metadata + Uc b-frags (5 slots: st = wave + 4*i)
  int srcs[5];
  float bv[5];
  short8 bfr[5];
  unsigned hotm = 0, coldm = 0;
#pragma unroll
  for (int i = 0; i < 5; ++i) {
    srcs[i] = KHOT; bv[i] = 0.f; bfr[i] = zero8;
    const int st = wave + 4 * i;
    if (st < NSUB) {
      const int v = c0 + st * 16 + col16;
      const int vc = (v < VOUT) ? v : (VOUT - 1);
      srcs[i] = o2n[vc];
      bv[i] = bias[vc];
      if (__any(srcs[i] < KHOT)) hotm |= (1u << i);
      if (__any(srcs[i] >= KHOT)) coldm |= (1u << i);
      if (srcs[i] >= KHOT)
        bfr[i] = *reinterpret_cast<const short8*>(Uc + (size_t)(srcs[i] - KHOT) * RCOLD + g4 * 8);
    }
  }
  __syncthreads();  // Fc ready (drains the prefetch loads; before any stores)

  for (int t = 0; t < 4; ++t) {
    int dw[4];
#pragma unroll
    for (int r = 0; r < 4; ++r) dw[r] = delta_row(n0 + t * 16 + g4 * 4 + r);
    const short8 afc = *reinterpret_cast<const short8*>(&Fc[t * 16 + col16][g4 * 8]);

    // ---- compute 5 subtile slots, scatter into shifted Epi ----
#pragma unroll
    for (int i = 0; i < 5; ++i) {
      const int st = wave + 4 * i;
      if (st >= NSUB) continue;  // wave-uniform
      f32x4 acc = (f32x4){0.f, 0.f, 0.f, 0.f};
      if (coldm & (1u << i))
        acc = __builtin_amdgcn_mfma_f32_16x16x32_bf16(afc, bfr[i], acc, 0, 0, 0);
      if (hotm & (1u << i)) {
#pragma unroll
        for (int ks = 0; ks < RHOT / 32; ++ks) {
          const short8 afh = *reinterpret_cast<const short8*>(
              F + (size_t)(n0 + t * 16 + col16) * RF + ks * 32 + g4 * 8);
          short8 aw = zero8;
          if (srcs[i] < KHOT)
            aw = *reinterpret_cast<const short8*>(Uh + (size_t)srcs[i] * RHOT + ks * 32 + g4 * 8);
          acc = __builtin_amdgcn_mfma_f32_16x16x32_bf16(afh, aw, acc, 0, 0, 0);
        }
      }
#pragma unroll
      for (int r = 0; r < 4; ++r) {
        const int p = st * 16 + col16 - dw[r];
        if (p >= 0 && p < CPB)
          Epi[g4 * 4 + r][p] = acc[r] * alpha + bv[i];
      }
    }

    // barrier: Epi writes visible; stores (none yet this chunk) NOT drained
    asm volatile("s_waitcnt lgkmcnt(0)" ::: "memory");
    __builtin_amdgcn_sched_barrier(0);
    __builtin_amdgcn_s_barrier();
    __builtin_amdgcn_sched_barrier(0);

    // ---- store: wave stores rows [4*wave, 4*wave+4), ONE aligned 1KB run each ----
#pragma unroll
    for (int rr = 0; rr < 4; ++rr) {
      const int row16 = wave * 4 + rr;
      const int n = n0 + t * 16 + row16;
      const int dn = delta_row(n);
      f32x4 vals = *reinterpret_cast<const f32x4*>(&Epi[row16][lane * 4]);
      const int c = c0 + dn + lane * 4;
      const size_t gr = (size_t)n * VOUT;
      if (c + 3 < VOUT) {
        *reinterpret_cast<f32x4*>(out + gr + c) = vals;
      } else {
#pragma unroll
        for (int q = 0; q < 4; ++q)
          if (c + q < VOUT) out[gr + c + q] = vals[q];
      }
    }

    // barrier: my Epi reads done before next chunk overwrites; stores stay in flight
    asm volatile("s_waitcnt lgkmcnt(0)" ::: "memory");
    __builtin_amdgcn_sched_barrier(0);
    __builtin_amdgcn_s_barrier();
    __builtin_amdgcn_sched_barrier(0);
  }

  // ---- head cleanup: cols [0, d(n)) (bx == 0 only) ----
  if (blockIdx.x == 0) {
    for (int idx = tid; idx < RPB * 32; idx += 256) {
      const int row = idx >> 5, cc = idx & 31;
      const int n = n0 + row;
      if (cc >= delta_row(n)) continue;
      const int src = o2n[cc];
      float sum = 0.f;
      if (src < KHOT) {
        const __hip_bfloat16* uh = Uh + (size_t)src * RHOT;
        const __hip_bfloat16* fr = F + (size_t)n * RF;
        for (int k = 0; k < RHOT; ++k)
          sum += __bfloat162float(uh[k]) * __bfloat162float(fr[k]);
      } else {
        const __hip_bfloat16* uc = Uc + (size_t)(src - KHOT) * RCOLD;
        const __hip_bfloat16* fr = F + (size_t)n * RF + RHOT;
        for (int k = 0; k < RCOLD; ++k)
          sum += __bfloat162float(uc[k]) * __bfloat162float(fr[k]);
      }
      out[(size_t)n * VOUT + cc] = sum * alpha + bias[cc];
    }
  }
}

extern "C" void kernel_launch(void* const* d_in, const int* in_sizes, int n_in,
                              void* d_out, int out_size, void* d_ws, size_t ws_size,
                              hipStream_t stream) {
  const int* tokens    = (const int*)d_in[0];
  const int* o2n       = (const int*)d_in[1];
  const float* B_hot   = (const float*)d_in[2];
  const float* B_cold  = (const float*)d_in[3];
  const float* U_hot   = (const float*)d_in[4];
  const float* U_cold  = (const float*)d_in[5];
  const float* log_a   = (const float*)d_in[6];
  const float* bias    = (const float*)d_in[7];
  float* out = (float*)d_out;

  const int N = in_sizes[0];  // 4096 tokens

  // workspace layout (bytes)
  char* ws = (char*)d_ws;
  __hip_bfloat16* Bmat = (__hip_bfloat16*)(ws + 0);             // 425984*2
  __hip_bfloat16* UhB  = (__hip_bfloat16*)(ws + (1u << 20));    // 393216*2
  __hip_bfloat16* UcB  = (__hip_bfloat16*)(ws + (2u << 20));    // 1575456*2
  float*          G    = (float*)(ws + (6u << 20));             // 416*416*4
  __hip_bfloat16* F    = (__hip_bfloat16*)(ws + (7u << 20));    // 4096*416*2

  k_convert<<<2048, 256, 0, stream>>>(B_hot, B_cold, U_hot, U_cold, Bmat, UhB, UcB);
  k_gram<<<169, 256, 0, stream>>>(Bmat, G);
  k_encode<<<N, 256, 0, stream>>>(tokens, o2n, U_hot, U_cold, G, F);

  dim3 grid((VOUT + CPB - 1) / CPB, N / RPB);
  k_out<<<grid, 256, 0, stream>>>(o2n, F, UhB, UcB, log_a, bias, out);
}

// Round 12
// 364.914 us; speedup vs baseline: 2.1254x; 1.0248x over previous
//
#include <hip/hip_runtime.h>
#include <hip/hip_bf16.h>

#define VOUT 50257
#define KHOT 1024
#define DIM  1024
#define RHOT 384
#define RCOLD 32
#define RF   416   // RHOT + RCOLD
#define NWIN 197   // col windows of 256
#define GRID 1024  // persistent marching blocks

typedef __attribute__((ext_vector_type(8))) short short8;
typedef __attribute__((ext_vector_type(4))) float f32x4;

__device__ __forceinline__ int delta_row(int n) {
  // smallest d>=0 with 17*n + d ≡ 0 (mod 32) => col (c0+d) of row n is 128B-aligned
  return (32 - ((17 * n) & 31)) & 31;
}

// ---------------- K0: convert f32 weights to bf16 ----------------
__global__ void k_convert(const float* __restrict__ Bh, const float* __restrict__ Bc,
                          const float* __restrict__ Uh, const float* __restrict__ Uc,
                          __hip_bfloat16* __restrict__ Bmat,
                          __hip_bfloat16* __restrict__ UhB,
                          __hip_bfloat16* __restrict__ UcB) {
  const int nBh = RHOT * DIM;
  const int nBm = RF * DIM;
  const int nUh = KHOT * RHOT;
  const int nUc = (VOUT - KHOT) * RCOLD;
  const int total = nBm + nUh + nUc;
  for (int i = blockIdx.x * blockDim.x + threadIdx.x; i < total;
       i += gridDim.x * blockDim.x) {
    if (i < nBm) {
      float v = (i < nBh) ? Bh[i] : Bc[i - nBh];
      Bmat[i] = __float2bfloat16(v);
    } else if (i < nBm + nUh) {
      UhB[i - nBm] = __float2bfloat16(Uh[i - nBm]);
    } else {
      int j = i - nBm - nUh;
      UcB[j] = __float2bfloat16(Uc[j]);
    }
  }
}

// ---------------- K1: G = Bmat @ Bmat^T ----------------
__global__ __launch_bounds__(256) void k_gram(const __hip_bfloat16* __restrict__ Bmat,
                                              float* __restrict__ G) {
  const int wave = threadIdx.x >> 6;
  const int lane = threadIdx.x & 63;
  const int idx = blockIdx.x * 4 + wave;
  if (idx >= 26 * 26) return;
  const int ti = idx / 26, tj = idx % 26;
  const int i0 = ti * 16, j0 = tj * 16;
  const int col16 = lane & 15;
  const int g4 = lane >> 4;

  f32x4 acc = (f32x4){0.f, 0.f, 0.f, 0.f};
  const __hip_bfloat16* arow = Bmat + (size_t)(i0 + col16) * DIM;
  const __hip_bfloat16* brow = Bmat + (size_t)(j0 + col16) * DIM;
#pragma unroll 4
  for (int ks = 0; ks < DIM / 32; ++ks) {
    short8 a = *reinterpret_cast<const short8*>(arow + ks * 32 + g4 * 8);
    short8 b = *reinterpret_cast<const short8*>(brow + ks * 32 + g4 * 8);
    acc = __builtin_amdgcn_mfma_f32_16x16x32_bf16(a, b, acc, 0, 0, 0);
  }
#pragma unroll
  for (int r = 0; r < 4; ++r)
    G[(size_t)(i0 + g4 * 4 + r) * RF + j0 + col16] = acc[r];
}

// ---------------- K2: per-token F[n] = u @ G ----------------
__global__ void k_encode(const int* __restrict__ tokens, const int* __restrict__ o2n,
                         const float* __restrict__ Uh, const float* __restrict__ Uc,
                         const float* __restrict__ G, __hip_bfloat16* __restrict__ F) {
  const int n = blockIdx.x;
  __shared__ float u[RHOT];
  const int tok = tokens[n];
  const int tn = o2n[tok];
  const bool hot = tn < KHOT;
  const int R = hot ? RHOT : RCOLD;
  const float* urow = hot ? (Uh + (size_t)tn * RHOT) : (Uc + (size_t)(tn - KHOT) * RCOLD);
  for (int r = threadIdx.x; r < R; r += blockDim.x) u[r] = urow[r];
  __syncthreads();
  const int gbase = hot ? 0 : RHOT;
  for (int c = threadIdx.x; c < RF; c += blockDim.x) {
    float acc = 0.f;
    for (int r = 0; r < R; ++r) acc += u[r] * G[(size_t)(gbase + r) * RF + c];
    F[(size_t)n * RF + c] = __float2bfloat16(acc);
  }
}

// ---------------- K3 v12: flat-marching 16KB chunks (fill-mimicking front) ----------------
// Chunk = 16 rows x 256 stored cols, enumerated band-major (= flat memory order).
// GRID=1024 persistent blocks grid-stride through chunks -> concurrent chunks are
// ~1024 consecutive flat positions = ~16MB marching write window (like the 6.8TB/s
// fill kernel). Aligned shifted store windows (amp 1.0, v9-proven). Next chunk's
// global loads issued BEFORE this chunk's stores (in-order vmcnt: load-waits don't
// drain stores). Raw s_barrier + lgkmcnt only.

#define STAGE_CHUNK(N0_, C0_, FSL, SRCS, BV, BFR)                                        \
  do {                                                                                   \
    {                                                                                    \
      const int row_ = (tid >> 2) & 15, ch_ = tid & 3;                                   \
      FSL = *reinterpret_cast<const short8*>(F + (size_t)((N0_) + row_) * RF + RHOT + ch_ * 8); \
    }                                                                                    \
    _Pragma("unroll") for (int i_ = 0; i_ < 5; ++i_) {                                   \
      const int st_ = wave + 4 * i_;                                                     \
      SRCS[i_] = KHOT; BV[i_] = 0.f; BFR[i_] = zero8;                                    \
      if (st_ < 18) {                                                                    \
        const int v_ = (C0_) + st_ * 16 + col16;                                         \
        const int vc_ = (v_ < VOUT) ? v_ : (VOUT - 1);                                   \
        SRCS[i_] = o2n[vc_];                                                             \
        BV[i_] = bias[vc_];                                                              \
        if (SRCS[i_] >= KHOT)                                                            \
          BFR[i_] = *reinterpret_cast<const short8*>(                                    \
              Uc + (size_t)(SRCS[i_] - KHOT) * RCOLD + g4 * 8);                          \
      }                                                                                  \
    }                                                                                    \
  } while (0)

__global__ __launch_bounds__(256) void k_out(const int* __restrict__ o2n,
                                             const __hip_bfloat16* __restrict__ F,
                                             const __hip_bfloat16* __restrict__ Uh,
                                             const __hip_bfloat16* __restrict__ Uc,
                                             const float* __restrict__ log_alpha,
                                             const float* __restrict__ bias,
                                             float* __restrict__ out, int totch) {
  __shared__ __hip_bfloat16 Fc[2][16][40];  // double-buffered F slice (2.5 KB)
  __shared__ float Epi[16][260];            // 16.6 KB
  const int tid = threadIdx.x;
  const int wave = tid >> 6;
  const int lane = tid & 63;
  const int col16 = lane & 15;
  const int g4 = lane >> 4;
  const float alpha = expf(log_alpha[0]);
  const short8 zero8 = (short8){0, 0, 0, 0, 0, 0, 0, 0};

  int c = blockIdx.x;
  if (c >= totch) return;
  int band = c / NWIN, win = c - band * NWIN;
  int n0 = band * 16, c0 = win * 256;

  short8 fsl;
  int srcs[5];
  float bv[5];
  short8 bfr[5];
  STAGE_CHUNK(n0, c0, fsl, srcs, bv, bfr);

  int buf = 0;
  for (;;) {
    // write Fc[buf] (tid<64), then barrier: Fc visible + prev store-phase Epi reads done
    if (tid < 64) {
      const int row = tid >> 2, ch = tid & 3;
      *reinterpret_cast<short8*>(&Fc[buf][row][ch * 8]) = fsl;
    }
    asm volatile("s_waitcnt lgkmcnt(0)" ::: "memory");
    __builtin_amdgcn_s_barrier();

    unsigned hotm = 0, coldm = 0;
#pragma unroll
    for (int i = 0; i < 5; ++i) {
      const int st = wave + 4 * i;
      if (st < 18) {
        if (__any(srcs[i] < KHOT)) hotm |= (1u << i);
        if (__any(srcs[i] >= KHOT)) coldm |= (1u << i);
      }
    }
    int dw[4];
#pragma unroll
    for (int r = 0; r < 4; ++r) dw[r] = delta_row(n0 + g4 * 4 + r);
    const short8 afc = *reinterpret_cast<const short8*>(&Fc[buf][col16][g4 * 8]);

    // compute + shifted Epi scatter
#pragma unroll
    for (int i = 0; i < 5; ++i) {
      const int st = wave + 4 * i;
      if (st >= 18) continue;  // wave-uniform
      f32x4 acc = (f32x4){0.f, 0.f, 0.f, 0.f};
      if (coldm & (1u << i))
        acc = __builtin_amdgcn_mfma_f32_16x16x32_bf16(afc, bfr[i], acc, 0, 0, 0);
      if (hotm & (1u << i)) {
#pragma unroll
        for (int ks = 0; ks < RHOT / 32; ++ks) {
          const short8 afh = *reinterpret_cast<const short8*>(
              F + (size_t)(n0 + col16) * RF + ks * 32 + g4 * 8);
          short8 aw = zero8;
          if (srcs[i] < KHOT)
            aw = *reinterpret_cast<const short8*>(Uh + (size_t)srcs[i] * RHOT + ks * 32 + g4 * 8);
          acc = __builtin_amdgcn_mfma_f32_16x16x32_bf16(afh, aw, acc, 0, 0, 0);
        }
      }
#pragma unroll
      for (int r = 0; r < 4; ++r) {
        const int p = st * 16 + col16 - dw[r];
        if (p >= 0 && p < 256)
          Epi[g4 * 4 + r][p] = acc[r] * alpha + bv[i];
      }
    }

    // stage NEXT chunk's global loads BEFORE the store phase
    const int cn = c + GRID;
    const bool more = cn < totch;
    int nband = 0, nwin = 0;
    short8 nfsl = zero8;
    int nsrcs[5];
    float nbv[5];
    short8 nbfr[5];
#pragma unroll
    for (int i = 0; i < 5; ++i) { nsrcs[i] = KHOT; nbv[i] = 0.f; nbfr[i] = zero8; }
    if (more) {
      nband = cn / NWIN;
      nwin = cn - nband * NWIN;
      const int nn0 = nband * 16, nc0 = nwin * 256;
      STAGE_CHUNK(nn0, nc0, nfsl, nsrcs, nbv, nbfr);
    }

    asm volatile("s_waitcnt lgkmcnt(0)" ::: "memory");
    __builtin_amdgcn_s_barrier();  // Epi visible

    // store phase: wave stores rows [4*wave, +4), ONE aligned 1KB run each
#pragma unroll
    for (int rr = 0; rr < 4; ++rr) {
      const int row16 = wave * 4 + rr;
      const int n = n0 + row16;
      const int dn = delta_row(n);
      f32x4 vals = *reinterpret_cast<const f32x4*>(&Epi[row16][lane * 4]);
      const int cc = c0 + dn + lane * 4;
      const size_t gr = (size_t)n * VOUT;
      if (cc + 3 < VOUT) {
        *reinterpret_cast<f32x4*>(out + gr + cc) = vals;
      } else {
#pragma unroll
        for (int q = 0; q < 4; ++q)
          if (cc + q < VOUT) out[gr + cc + q] = vals[q];
      }
    }

    // head cleanup for win==0 chunks: cols [0, d(n)) scalar (rare: 1/197)
    if (win == 0) {
      for (int idx = tid; idx < 16 * 32; idx += 256) {
        const int row = idx >> 5, ccc = idx & 31;
        const int n = n0 + row;
        if (ccc >= delta_row(n)) continue;
        const int src = o2n[ccc];
        float sum = 0.f;
        if (src < KHOT) {
          const __hip_bfloat16* uh = Uh + (size_t)src * RHOT;
          const __hip_bfloat16* fr = F + (size_t)n * RF;
          for (int k = 0; k < RHOT; ++k)
            sum += __bfloat162float(uh[k]) * __bfloat162float(fr[k]);
        } else {
          const __hip_bfloat16* uc = Uc + (size_t)(src - KHOT) * RCOLD;
          const __hip_bfloat16* fr = F + (size_t)n * RF + RHOT;
          for (int k = 0; k < RCOLD; ++k)
            sum += __bfloat162float(uc[k]) * __bfloat162float(fr[k]);
        }
        out[(size_t)n * VOUT + ccc] = sum * alpha + bias[ccc];
      }
    }

    if (!more) break;
    c = cn; band = nband; win = nwin; n0 = band * 16; c0 = win * 256;
    fsl = nfsl;
#pragma unroll
    for (int i = 0; i < 5; ++i) { srcs[i] = nsrcs[i]; bv[i] = nbv[i]; bfr[i] = nbfr[i]; }
    buf ^= 1;
  }
}

extern "C" void kernel_launch(void* const* d_in, const int* in_sizes, int n_in,
                              void* d_out, int out_size, void* d_ws, size_t ws_size,
                              hipStream_t stream) {
  const int* tokens    = (const int*)d_in[0];
  const int* o2n       = (const int*)d_in[1];
  const float* B_hot   = (const float*)d_in[2];
  const float* B_cold  = (const float*)d_in[3];
  const float* U_hot   = (const float*)d_in[4];
  const float* U_cold  = (const float*)d_in[5];
  const float* log_a   = (const float*)d_in[6];
  const float* bias    = (const float*)d_in[7];
  float* out = (float*)d_out;

  const int N = in_sizes[0];  // 4096 tokens

  char* ws = (char*)d_ws;
  __hip_bfloat16* Bmat = (__hip_bfloat16*)(ws + 0);
  __hip_bfloat16* UhB  = (__hip_bfloat16*)(ws + (1u << 20));
  __hip_bfloat16* UcB  = (__hip_bfloat16*)(ws + (2u << 20));
  float*          G    = (float*)(ws + (6u << 20));
  __hip_bfloat16* F    = (__hip_bfloat16*)(ws + (7u << 20));

  k_convert<<<2048, 256, 0, stream>>>(B_hot, B_cold, U_hot, U_cold, Bmat, UhB, UcB);
  k_gram<<<169, 256, 0, stream>>>(Bmat, G);
  k_encode<<<N, 256, 0, stream>>>(tokens, o2n, U_hot, U_cold, G, F);

  const int totch = (N / 16) * NWIN;  // 50432
  k_out<<<GRID, 256, 0, stream>>>(o2n, F, UhB, UcB, log_a, bias, out, totch);
}